// Round 1
// baseline (15454.803 us; speedup 1.0000x reference)
//
#include <hip/hip_runtime.h>
#include <math.h>

#define NB 256
#define TT 64
#define DD 1024
#define HH 1024

// ---------------- K0: h0 = c0 = mean over 16 locations ----------------
__global__ void k_init(const float* __restrict__ A,
                       float* __restrict__ h0,
                       float* __restrict__ c0) {
    int idx = blockIdx.x * blockDim.x + threadIdx.x;  // 0 .. N*H-1
    const float* ap = A + (size_t)idx * 16;
    float s = 0.f;
#pragma unroll
    for (int l = 0; l < 16; ++l) s += ap[l];
    s *= (1.f / 16.f);
    h0[idx] = s;
    c0[idx] = s;
}

// ---------------- K1: attention over the 4x4 grid ----------------
// grid = N blocks, 256 threads. Each thread handles 4 h-indices.
__global__ void k_attn(const float* __restrict__ A,
                       const float* __restrict__ hprev, long long hstride,
                       float* __restrict__ attn) {
    const int n = blockIdx.x;
    const int tid = threadIdx.x;
    const float* An = A + (size_t)n * HH * 16;
    const float* hn = hprev + (size_t)n * hstride;

    float a[4][16];
    float s[16];
#pragma unroll
    for (int l = 0; l < 16; ++l) s[l] = 0.f;

#pragma unroll
    for (int i = 0; i < 4; ++i) {
        int h = tid + i * 256;
        float hv = hn[h];
        const float4* ap = (const float4*)(An + (size_t)h * 16);
        float4 v0 = ap[0], v1 = ap[1], v2 = ap[2], v3 = ap[3];
        a[i][0] = v0.x; a[i][1] = v0.y; a[i][2] = v0.z; a[i][3] = v0.w;
        a[i][4] = v1.x; a[i][5] = v1.y; a[i][6] = v1.z; a[i][7] = v1.w;
        a[i][8] = v2.x; a[i][9] = v2.y; a[i][10] = v2.z; a[i][11] = v2.w;
        a[i][12] = v3.x; a[i][13] = v3.y; a[i][14] = v3.z; a[i][15] = v3.w;
#pragma unroll
        for (int l = 0; l < 16; ++l) s[l] += hv * a[i][l];
    }

    // block reduction of s[16] over 256 threads; layout red[l*256 + tid]
    __shared__ float red[16 * 256];
#pragma unroll
    for (int l = 0; l < 16; ++l) red[l * 256 + tid] = s[l];
    __syncthreads();
    for (int st = 128; st > 0; st >>= 1) {
        if (tid < st) {
#pragma unroll
            for (int l = 0; l < 16; ++l)
                red[l * 256 + tid] += red[l * 256 + tid + st];
        }
        __syncthreads();
    }

    const float scale = 0.03125f;  // 1/sqrt(1024)
    float sv[16];
#pragma unroll
    for (int l = 0; l < 16; ++l) sv[l] = red[l * 256] * scale;
    float mx = sv[0];
#pragma unroll
    for (int l = 1; l < 16; ++l) mx = fmaxf(mx, sv[l]);
    float e[16], sum = 0.f;
#pragma unroll
    for (int l = 0; l < 16; ++l) { e[l] = expf(sv[l] - mx); sum += e[l]; }
    float inv = 1.f / sum;
#pragma unroll
    for (int l = 0; l < 16; ++l) e[l] *= inv;

#pragma unroll
    for (int i = 0; i < 4; ++i) {
        int h = tid + i * 256;
        float acc = 0.f;
#pragma unroll
        for (int l = 0; l < 16; ++l) acc += a[i][l] * e[l];
        attn[(size_t)n * HH + h] = acc;
    }
}

// ---------------- K2: fused step GEMM + gates ----------------
// a[n, j+g*1024] = sum_k lhs[n,k] * W[k, j+g*1024],  lhs = [h | attn | x_t]
// grid = (4, 64): mi = n-block of 64 rows, ni = j-block of 16 cols.
// 512 threads: col = tid&63 (a-col: g = col>>4, jj = col&15), rg = tid>>6 (8 rows).
__global__ __launch_bounds__(512) void k_step(
    const float* __restrict__ hprev, long long hstride,
    const float* __restrict__ attn,
    const float* __restrict__ x_t,  // x + t*DD, row stride TT*DD
    const float* __restrict__ Wh, const float* __restrict__ Wattn,
    const float* __restrict__ Wx, const float* __restrict__ b,
    float* __restrict__ c,
    float* __restrict__ hout /* out + t*HH, row stride TT*HH */) {
    const int mi = blockIdx.x;        // 0..3
    const int ni = blockIdx.y;        // 0..63
    const int tid = threadIdx.x;
    const int col = tid & 63;
    const int rg = tid >> 6;
    const int jj = col & 15;
    const int g = col >> 4;
    const int nbase = mi * 64;
    const int jbase = ni * 16;
    const int jcol = jbase + jj + g * 1024;

    __shared__ float lhs[64 * 68];  // [k][row], pad 68
    __shared__ float as[64 * 64];   // [row][acol]

    float acc[8];
#pragma unroll
    for (int m = 0; m < 8; ++m) acc[m] = 0.f;

    for (int kc = 0; kc < 48; ++kc) {
        const int kbase = kc * 64;
        __syncthreads();  // previous iter's lhs reads done
        // stage lhs chunk: 64 rows x 64 k = 1024 float4
#pragma unroll
        for (int i = 0; i < 2; ++i) {
            int q = i * 512 + tid;
            int row = q >> 4;
            int ko4 = q & 15;
            int k = kbase + ko4 * 4;
            const float* src;
            if (k < 1024)
                src = hprev + (size_t)(nbase + row) * hstride + k;
            else if (k < 2048)
                src = attn + (size_t)(nbase + row) * HH + (k - 1024);
            else
                src = x_t + (size_t)(nbase + row) * (TT * DD) + (k - 2048);
            float4 v = *(const float4*)src;
            float* d = &lhs[(ko4 * 4) * 68 + row];
            d[0] = v.x; d[68] = v.y; d[136] = v.z; d[204] = v.w;
        }
        __syncthreads();

        const float* Wp;
        if (kbase < 1024)       Wp = Wh + (size_t)kbase * 4096 + jcol;
        else if (kbase < 2048)  Wp = Wattn + (size_t)(kbase - 1024) * 4096 + jcol;
        else                    Wp = Wx + (size_t)(kbase - 2048) * 4096 + jcol;

#pragma unroll 8
        for (int kk = 0; kk < 64; ++kk) {
            float wv = Wp[(size_t)kk * 4096];
            const float4* lp = (const float4*)&lhs[kk * 68 + rg * 8];
            float4 l0 = lp[0], l1 = lp[1];
            acc[0] += l0.x * wv; acc[1] += l0.y * wv;
            acc[2] += l0.z * wv; acc[3] += l0.w * wv;
            acc[4] += l1.x * wv; acc[5] += l1.y * wv;
            acc[6] += l1.z * wv; acc[7] += l1.w * wv;
        }
    }

    // write partial a-tile to LDS and recombine gates
#pragma unroll
    for (int m = 0; m < 8; ++m) as[(rg * 8 + m) * 64 + col] = acc[m];
    __syncthreads();

#pragma unroll
    for (int i = 0; i < 2; ++i) {
        int q = i * 512 + tid;  // 0..1023 cells
        int row = q >> 4;
        int j2 = q & 15;
        int n = nbase + row;
        int j = jbase + j2;
        float ai = as[row * 64 + j2 + 0]  + b[j];
        float af = as[row * 64 + j2 + 16] + b[j + 1024];
        float ao = as[row * 64 + j2 + 32] + b[j + 2048];
        float ag = as[row * 64 + j2 + 48] + b[j + 3072];
        float iv = 1.f / (1.f + expf(-ai));
        float fv = 1.f / (1.f + expf(-af));
        float ov = 1.f / (1.f + expf(-ao));
        float gv = tanhf(ag);
        float cc = c[(size_t)n * HH + j];
        float cn = fv * cc + iv * gv;
        c[(size_t)n * HH + j] = cn;
        hout[(size_t)n * (TT * HH) + j] = ov * tanhf(cn);
    }
}

extern "C" void kernel_launch(void* const* d_in, const int* in_sizes, int n_in,
                              void* d_out, int out_size, void* d_ws, size_t ws_size,
                              hipStream_t stream) {
    const float* x     = (const float*)d_in[0];
    const float* A     = (const float*)d_in[1];
    const float* Wx    = (const float*)d_in[2];
    const float* Wh    = (const float*)d_in[3];
    const float* Wattn = (const float*)d_in[4];
    const float* b     = (const float*)d_in[5];
    float* out = (float*)d_out;

    float* attn = (float*)d_ws;          // N*H
    float* h0   = attn + (size_t)NB * HH;  // N*H
    float* c    = h0 + (size_t)NB * HH;    // N*H

    k_init<<<(NB * HH) / 256, 256, 0, stream>>>(A, h0, c);

    for (int t = 0; t < TT; ++t) {
        const float* hprev = (t == 0) ? h0 : out + (size_t)(t - 1) * HH;
        long long hstride = (t == 0) ? (long long)HH : (long long)TT * HH;
        k_attn<<<NB, 256, 0, stream>>>(A, hprev, hstride, attn);
        k_step<<<dim3(4, 64), 512, 0, stream>>>(
            hprev, hstride, attn, x + (size_t)t * DD,
            Wh, Wattn, Wx, b, c, out + (size_t)t * HH);
    }
}

// Round 2
// 3656.530 us; speedup vs baseline: 4.2266x; 4.2266x over previous
//
#include <hip/hip_runtime.h>
#include <math.h>

#define NB 256
#define TT 64
#define DD 1024
#define HH 1024

typedef __attribute__((ext_vector_type(8))) short short8;
typedef __attribute__((ext_vector_type(4))) float floatx4;

__device__ inline unsigned short f2bf(float f) {
    unsigned int u = __builtin_bit_cast(unsigned int, f);
    u += 0x7fffu + ((u >> 16) & 1u);
    return (unsigned short)(u >> 16);
}
__device__ inline float bf2f(unsigned int h16) {
    unsigned int u = h16 << 16;
    return __builtin_bit_cast(float, u);
}

__device__ inline void async_copy16(const unsigned short* g, unsigned short* l) {
    __builtin_amdgcn_global_load_lds(
        (const __attribute__((address_space(1))) unsigned int*)(g),
        (__attribute__((address_space(3))) unsigned int*)(l), 16, 0, 0);
}

// ---------------- conv W: fp32 [k][4096] -> bf16 B-fragment tiles ----------------
// W_sw tile (ni 0..31, kc 0..47): 1024 units of 16B; unit = kq*128 + cc;
// unit holds W[k = kc*64+kq*8 + j][col = (cc>>5)*1024 + ni*32 + (cc&31)], j=0..7.
__global__ void k_convW(const float* __restrict__ Wh,
                        const float* __restrict__ Wattn,
                        const float* __restrict__ Wx,
                        unsigned short* __restrict__ Wsw) {
    int u = blockIdx.x * 256 + threadIdx.x;  // 0 .. 32*48*1024-1
    int tile = u >> 10;
    int ni = tile / 48, kc = tile % 48;
    int kq = (u >> 7) & 7, cc = u & 127;
    int k = kc * 64 + kq * 8;
    int col = (cc >> 5) * 1024 + ni * 32 + (cc & 31);
    const float* src;
    if (k < 1024)       src = Wh    + (size_t)k * 4096 + col;
    else if (k < 2048)  src = Wattn + (size_t)(k - 1024) * 4096 + col;
    else                src = Wx    + (size_t)(k - 2048) * 4096 + col;
    unsigned int w[4];
#pragma unroll
    for (int j = 0; j < 4; ++j) {
        unsigned int lo = f2bf(src[(size_t)(2 * j) * 4096]);
        unsigned int hi = f2bf(src[(size_t)(2 * j + 1) * 4096]);
        w[j] = lo | (hi << 16);
    }
    ((uint4*)Wsw)[u] = make_uint4(w[0], w[1], w[2], w[3]);
}

// ---------------- conv x: fp32 [m][t][d] -> bf16 A-fragment layout ----------------
// xF unit index = t*32768 + kq*256 + m ; holds x[m][t][kq*8 + j], j=0..7
__global__ void k_convX(const float* __restrict__ x, unsigned short* __restrict__ xF) {
    int u = blockIdx.x * 256 + threadIdx.x;  // 0 .. 64*128*256-1
    int t = u >> 15;
    int kq = (u >> 8) & 127;
    int m = u & 255;
    const float* src = x + (size_t)m * (TT * DD) + t * DD + kq * 8;
    float4 v0 = ((const float4*)src)[0];
    float4 v1 = ((const float4*)src)[1];
    unsigned int w0 = f2bf(v0.x) | (f2bf(v0.y) << 16);
    unsigned int w1 = f2bf(v0.z) | (f2bf(v0.w) << 16);
    unsigned int w2 = f2bf(v1.x) | (f2bf(v1.y) << 16);
    unsigned int w3 = f2bf(v1.z) | (f2bf(v1.w) << 16);
    ((uint4*)xF)[u] = make_uint4(w0, w1, w2, w3);
}

// ---------------- conv A -> bf16, plus h0 = c0 = mean ----------------
__global__ void k_convA_init(const float* __restrict__ A,
                             unsigned short* __restrict__ Abf,
                             float* __restrict__ h0,
                             float* __restrict__ c) {
    int idx = blockIdx.x * 256 + threadIdx.x;  // n*1024 + h
    const float4* ap = (const float4*)(A + (size_t)idx * 16);
    float4 v0 = ap[0], v1 = ap[1], v2 = ap[2], v3 = ap[3];
    float vs[16] = {v0.x, v0.y, v0.z, v0.w, v1.x, v1.y, v1.z, v1.w,
                    v2.x, v2.y, v2.z, v2.w, v3.x, v3.y, v3.z, v3.w};
    float s = 0.f;
    unsigned int w[8];
#pragma unroll
    for (int j = 0; j < 8; ++j) {
        s += vs[2 * j] + vs[2 * j + 1];
        w[j] = f2bf(vs[2 * j]) | (f2bf(vs[2 * j + 1]) << 16);
    }
    ((uint4*)Abf)[idx * 2]     = make_uint4(w[0], w[1], w[2], w[3]);
    ((uint4*)Abf)[idx * 2 + 1] = make_uint4(w[4], w[5], w[6], w[7]);
    s *= (1.f / 16.f);
    h0[idx] = s;
    c[idx] = s;
}

// ---------------- k_attn: attention + write h/attn into lhs fragment buffer ----------
// lhsF unit = kq*256 + n (kq 0..127 = h features, 128..255 = attn features)
__global__ __launch_bounds__(256) void k_attn(
    const unsigned short* __restrict__ Abf,
    const float* __restrict__ hprev, int hstride,
    unsigned short* __restrict__ lhsF) {
    const int n = blockIdx.x;
    const int tid = threadIdx.x;

    float4 hv = *(const float4*)(hprev + (size_t)n * hstride + tid * 4);
    const uint4* ar = (const uint4*)(Abf + ((size_t)n * 1024 + tid * 4) * 16);

    float a[4][16];
#pragma unroll
    for (int r = 0; r < 4; ++r) {
        uint4 p0 = ar[r * 2], p1 = ar[r * 2 + 1];
        unsigned int ws[8] = {p0.x, p0.y, p0.z, p0.w, p1.x, p1.y, p1.z, p1.w};
#pragma unroll
        for (int j = 0; j < 8; ++j) {
            a[r][2 * j]     = bf2f(ws[j] & 0xffffu);
            a[r][2 * j + 1] = bf2f(ws[j] >> 16);
        }
    }
    float hvv[4] = {hv.x, hv.y, hv.z, hv.w};
    float s[16];
#pragma unroll
    for (int l = 0; l < 16; ++l) {
        float t = 0.f;
#pragma unroll
        for (int r = 0; r < 4; ++r) t += hvv[r] * a[r][l];
        s[l] = t;
    }

    __shared__ float red[16 * 256];
#pragma unroll
    for (int l = 0; l < 16; ++l) red[l * 256 + tid] = s[l];
    __syncthreads();
    for (int st = 128; st > 0; st >>= 1) {
        if (tid < st) {
#pragma unroll
            for (int l = 0; l < 16; ++l)
                red[l * 256 + tid] += red[l * 256 + tid + st];
        }
        __syncthreads();
    }

    const float scale = 0.03125f;  // 1/sqrt(1024)
    float sv[16];
#pragma unroll
    for (int l = 0; l < 16; ++l) sv[l] = red[l * 256] * scale;
    float mx = sv[0];
#pragma unroll
    for (int l = 1; l < 16; ++l) mx = fmaxf(mx, sv[l]);
    float e[16], sum = 0.f;
#pragma unroll
    for (int l = 0; l < 16; ++l) { e[l] = __expf(sv[l] - mx); sum += e[l]; }
    float inv = 1.f / sum;
#pragma unroll
    for (int l = 0; l < 16; ++l) e[l] *= inv;

    // attn for this thread's 4 features + bf16 h, into fragment layout
    unsigned short hb[4], ab[4];
#pragma unroll
    for (int r = 0; r < 4; ++r) {
        float acc = 0.f;
#pragma unroll
        for (int l = 0; l < 16; ++l) acc += a[r][l] * e[l];
        ab[r] = f2bf(acc);
        hb[r] = f2bf(hvv[r]);
    }
    unsigned int hw0 = (unsigned int)hb[0] | ((unsigned int)hb[1] << 16);
    unsigned int hw1 = (unsigned int)hb[2] | ((unsigned int)hb[3] << 16);
    unsigned int aw0 = (unsigned int)ab[0] | ((unsigned int)ab[1] << 16);
    unsigned int aw1 = (unsigned int)ab[2] | ((unsigned int)ab[3] << 16);
    size_t hu = ((size_t)(tid >> 1) * 256 + n) * 8 + (size_t)(tid & 1) * 4;
    size_t au = ((size_t)(128 + (tid >> 1)) * 256 + n) * 8 + (size_t)(tid & 1) * 4;
    *(uint2*)(lhsF + hu) = make_uint2(hw0, hw1);
    *(uint2*)(lhsF + au) = make_uint2(aw0, aw1);
}

// ---------------- k_step: bf16 MFMA GEMM + LSTM gates ----------------
// grid (32, 2): ni = blockIdx.x (32 j's x 4 gates = 128 cols), mi = blockIdx.y (128 rows)
// 256 threads = 4 waves: wm = wave&1 (64-row half), wn = wave>>1 (16-j half)
__global__ __launch_bounds__(256) void k_step(
    const unsigned short* __restrict__ lhsF,
    const unsigned short* __restrict__ xFt,   // xF + t*262144
    const unsigned short* __restrict__ Wsw,
    const float* __restrict__ b,
    float* __restrict__ c,
    float* __restrict__ out_t) {              // out + t*HH, row stride TT*HH
    const int ni = blockIdx.x, mi = blockIdx.y;
    const int tid = threadIdx.x;
    const int wave = tid >> 6, lane = tid & 63;
    const int wm = wave & 1, wn = wave >> 1;
    const int l15 = lane & 15, quad = lane >> 4;

    __shared__ __align__(16) unsigned short ldsA[8192];  // 16 KB: unit = kq*128 + mm
    __shared__ __align__(16) unsigned short ldsB[8192];  // 16 KB: unit = kq*128 + cc

    floatx4 acc[4][4];
#pragma unroll
    for (int mt = 0; mt < 4; ++mt)
#pragma unroll
        for (int nt = 0; nt < 4; ++nt) acc[mt][nt] = (floatx4)0.f;

    const unsigned short* wTile = Wsw + (size_t)ni * 48 * 1024 * 8;
    const int waveBase = tid & ~63;

    for (int kc = 0; kc < 48; ++kc) {
        const unsigned short* aSrc = (kc < 32)
            ? lhsF + (size_t)kc * 2048 * 8
            : xFt + (size_t)(kc - 32) * 2048 * 8;
        const unsigned short* bSrc = wTile + (size_t)kc * 1024 * 8;
        __syncthreads();
#pragma unroll
        for (int i = 0; i < 4; ++i) {
            int idx = i * 256 + tid;
            int kq = idx >> 7, mm = idx & 127;
            async_copy16(aSrc + ((size_t)kq * 256 + mi * 128 + mm) * 8,
                         ldsA + (size_t)(i * 256 + waveBase) * 8);
            async_copy16(bSrc + (size_t)idx * 8,
                         ldsB + (size_t)(i * 256 + waveBase) * 8);
        }
        __syncthreads();
#pragma unroll
        for (int ks = 0; ks < 2; ++ks) {
            const int kqq = ks * 4 + quad;
            short8 af[4], bfr[4];
#pragma unroll
            for (int mt = 0; mt < 4; ++mt)
                af[mt] = *(const short8*)(ldsA + (size_t)(kqq * 128 + wm * 64 + mt * 16 + l15) * 8);
#pragma unroll
            for (int nt = 0; nt < 4; ++nt)
                bfr[nt] = *(const short8*)(ldsB + (size_t)(kqq * 128 + nt * 32 + wn * 16 + l15) * 8);
#pragma unroll
            for (int mt = 0; mt < 4; ++mt)
#pragma unroll
                for (int nt = 0; nt < 4; ++nt)
                    acc[mt][nt] = __builtin_amdgcn_mfma_f32_16x16x32_bf16(
                        af[mt], bfr[nt], acc[mt][nt], 0, 0, 0);
        }
    }

    // epilogue: gates in registers (nt = gate), c/h update
    const int jj = ni * 32 + wn * 16 + l15;
    const float bi = b[jj], bff = b[1024 + jj], bo = b[2048 + jj], bg = b[3072 + jj];
#pragma unroll
    for (int mt = 0; mt < 4; ++mt) {
#pragma unroll
        for (int r = 0; r < 4; ++r) {
            int row = mi * 128 + wm * 64 + mt * 16 + quad * 4 + r;
            float ai = acc[mt][0][r] + bi;
            float af_ = acc[mt][1][r] + bff;
            float ao = acc[mt][2][r] + bo;
            float ag = acc[mt][3][r] + bg;
            float iv = 1.f / (1.f + __expf(-ai));
            float fv = 1.f / (1.f + __expf(-af_));
            float ov = 1.f / (1.f + __expf(-ao));
            float gv = 1.f - 2.f / (__expf(2.f * ag) + 1.f);
            size_t ci = (size_t)row * HH + jj;
            float cold = c[ci];
            float cn = fv * cold + iv * gv;
            c[ci] = cn;
            float th = 1.f - 2.f / (__expf(2.f * cn) + 1.f);
            out_t[(size_t)row * (TT * HH) + jj] = ov * th;
        }
    }
}

extern "C" void kernel_launch(void* const* d_in, const int* in_sizes, int n_in,
                              void* d_out, int out_size, void* d_ws, size_t ws_size,
                              hipStream_t stream) {
    const float* x     = (const float*)d_in[0];
    const float* A     = (const float*)d_in[1];
    const float* Wx    = (const float*)d_in[2];
    const float* Wh    = (const float*)d_in[3];
    const float* Wattn = (const float*)d_in[4];
    const float* b     = (const float*)d_in[5];
    float* out = (float*)d_out;

    char* w = (char*)d_ws;
    unsigned short* Wsw  = (unsigned short*)(w);                 // 25,165,824 B
    unsigned short* xF   = (unsigned short*)(w + 25165824);      // 33,554,432 B
    unsigned short* lhsF = (unsigned short*)(w + 58720256);      //  1,048,576 B
    unsigned short* Abf  = (unsigned short*)(w + 59768832);      //  8,388,608 B
    float* h0            = (float*)(w + 68157440);               //  1,048,576 B
    float* c             = (float*)(w + 69206016);               //  1,048,576 B

    k_convW<<<6144, 256, 0, stream>>>(Wh, Wattn, Wx, Wsw);
    k_convX<<<8192, 256, 0, stream>>>(x, xF);
    k_convA_init<<<1024, 256, 0, stream>>>(A, Abf, h0, c);

    for (int t = 0; t < TT; ++t) {
        const float* hprev = (t == 0) ? h0 : out + (size_t)(t - 1) * HH;
        int hstride = (t == 0) ? HH : TT * HH;
        k_attn<<<NB, 256, 0, stream>>>(Abf, hprev, hstride, lhsF);
        k_step<<<dim3(32, 2), 256, 0, stream>>>(
            lhsF, xF + (size_t)t * 262144, Wsw, b, c, out + (size_t)t * HH);
    }
}

// Round 3
// 3298.989 us; speedup vs baseline: 4.6847x; 1.1084x over previous
//
#include <hip/hip_runtime.h>
#include <math.h>

#define NB 256
#define TT 64
#define DD 1024
#define HH 1024

typedef __attribute__((ext_vector_type(8))) short short8;
typedef __attribute__((ext_vector_type(4))) float floatx4;

__device__ inline unsigned short f2bf(float f) {
    unsigned int u = __builtin_bit_cast(unsigned int, f);
    u += 0x7fffu + ((u >> 16) & 1u);
    return (unsigned short)(u >> 16);
}
__device__ inline float bf2f(unsigned int h16) {
    unsigned int u = h16 << 16;
    return __builtin_bit_cast(float, u);
}

__device__ inline void async_copy16(const unsigned short* g, unsigned short* l) {
    __builtin_amdgcn_global_load_lds(
        (const __attribute__((address_space(1))) unsigned int*)(g),
        (__attribute__((address_space(3))) unsigned int*)(l), 16, 0, 0);
}

// ---------------- conv W: fp32 [k][4096] -> bf16 B-fragment tiles ----------------
// W_sw tile (ni 0..31, kc 0..47): 1024 units of 16B; unit = kq*128 + cc;
// unit holds W[k = kc*64+kq*8 + j][col = (cc>>5)*1024 + ni*32 + (cc&31)], j=0..7.
__global__ void k_convW(const float* __restrict__ Wh,
                        const float* __restrict__ Wattn,
                        const float* __restrict__ Wx,
                        unsigned short* __restrict__ Wsw) {
    int u = blockIdx.x * 256 + threadIdx.x;  // 0 .. 32*48*1024-1
    int tile = u >> 10;
    int ni = tile / 48, kc = tile % 48;
    int kq = (u >> 7) & 7, cc = u & 127;
    int k = kc * 64 + kq * 8;
    int col = (cc >> 5) * 1024 + ni * 32 + (cc & 31);
    const float* src;
    if (k < 1024)       src = Wh    + (size_t)k * 4096 + col;
    else if (k < 2048)  src = Wattn + (size_t)(k - 1024) * 4096 + col;
    else                src = Wx    + (size_t)(k - 2048) * 4096 + col;
    unsigned int w[4];
#pragma unroll
    for (int j = 0; j < 4; ++j) {
        unsigned int lo = f2bf(src[(size_t)(2 * j) * 4096]);
        unsigned int hi = f2bf(src[(size_t)(2 * j + 1) * 4096]);
        w[j] = lo | (hi << 16);
    }
    ((uint4*)Wsw)[u] = make_uint4(w[0], w[1], w[2], w[3]);
}

// ---------------- conv A -> bf16, plus h0 = c0 = mean ----------------
__global__ void k_convA_init(const float* __restrict__ A,
                             unsigned short* __restrict__ Abf,
                             float* __restrict__ h0,
                             float* __restrict__ c) {
    int idx = blockIdx.x * 256 + threadIdx.x;  // n*1024 + h
    const float4* ap = (const float4*)(A + (size_t)idx * 16);
    float4 v0 = ap[0], v1 = ap[1], v2 = ap[2], v3 = ap[3];
    float vs[16] = {v0.x, v0.y, v0.z, v0.w, v1.x, v1.y, v1.z, v1.w,
                    v2.x, v2.y, v2.z, v2.w, v3.x, v3.y, v3.z, v3.w};
    float s = 0.f;
    unsigned int w[8];
#pragma unroll
    for (int j = 0; j < 8; ++j) {
        s += vs[2 * j] + vs[2 * j + 1];
        w[j] = f2bf(vs[2 * j]) | (f2bf(vs[2 * j + 1]) << 16);
    }
    ((uint4*)Abf)[idx * 2]     = make_uint4(w[0], w[1], w[2], w[3]);
    ((uint4*)Abf)[idx * 2 + 1] = make_uint4(w[4], w[5], w[6], w[7]);
    s *= (1.f / 16.f);
    h0[idx] = s;
    c[idx] = s;
}

// ---------------- k_attn: attention + write h/attn into lhs fragment buffer ----------
// lhsF unit = kq*256 + n (kq 0..127 = h features, 128..255 = attn features)
__global__ __launch_bounds__(256) void k_attn(
    const unsigned short* __restrict__ Abf,
    const float* __restrict__ hprev, int hstride,
    unsigned short* __restrict__ lhsF) {
    const int n = blockIdx.x;
    const int tid = threadIdx.x;
    const int lane = tid & 63, wave = tid >> 6;

    float4 hv = *(const float4*)(hprev + (size_t)n * hstride + tid * 4);
    const uint4* ar = (const uint4*)(Abf + ((size_t)n * 1024 + tid * 4) * 16);

    float a[4][16];
#pragma unroll
    for (int r = 0; r < 4; ++r) {
        uint4 p0 = ar[r * 2], p1 = ar[r * 2 + 1];
        unsigned int ws[8] = {p0.x, p0.y, p0.z, p0.w, p1.x, p1.y, p1.z, p1.w};
#pragma unroll
        for (int j = 0; j < 8; ++j) {
            a[r][2 * j]     = bf2f(ws[j] & 0xffffu);
            a[r][2 * j + 1] = bf2f(ws[j] >> 16);
        }
    }
    float hvv[4] = {hv.x, hv.y, hv.z, hv.w};
    float s[16];
#pragma unroll
    for (int l = 0; l < 16; ++l) {
        float t = 0.f;
#pragma unroll
        for (int r = 0; r < 4; ++r) t += hvv[r] * a[r][l];
        s[l] = t;
    }

    // 64-lane butterfly reduction, then combine 4 waves through LDS
#pragma unroll
    for (int off = 32; off > 0; off >>= 1) {
#pragma unroll
        for (int l = 0; l < 16; ++l) s[l] += __shfl_xor(s[l], off, 64);
    }
    __shared__ float wred[4 * 16];
    if (lane == 0) {
#pragma unroll
        for (int l = 0; l < 16; ++l) wred[wave * 16 + l] = s[l];
    }
    __syncthreads();

    const float scale = 0.03125f;  // 1/sqrt(1024)
    float sv[16];
#pragma unroll
    for (int l = 0; l < 16; ++l)
        sv[l] = (wred[l] + wred[16 + l] + wred[32 + l] + wred[48 + l]) * scale;
    float mx = sv[0];
#pragma unroll
    for (int l = 1; l < 16; ++l) mx = fmaxf(mx, sv[l]);
    float e[16], sum = 0.f;
#pragma unroll
    for (int l = 0; l < 16; ++l) { e[l] = __expf(sv[l] - mx); sum += e[l]; }
    float inv = 1.f / sum;
#pragma unroll
    for (int l = 0; l < 16; ++l) e[l] *= inv;

    unsigned short hb[4], ab[4];
#pragma unroll
    for (int r = 0; r < 4; ++r) {
        float acc = 0.f;
#pragma unroll
        for (int l = 0; l < 16; ++l) acc += a[r][l] * e[l];
        ab[r] = f2bf(acc);
        hb[r] = f2bf(hvv[r]);
    }
    unsigned int hw0 = (unsigned int)hb[0] | ((unsigned int)hb[1] << 16);
    unsigned int hw1 = (unsigned int)hb[2] | ((unsigned int)hb[3] << 16);
    unsigned int aw0 = (unsigned int)ab[0] | ((unsigned int)ab[1] << 16);
    unsigned int aw1 = (unsigned int)ab[2] | ((unsigned int)ab[3] << 16);
    size_t hu = ((size_t)(tid >> 1) * 256 + n) * 8 + (size_t)(tid & 1) * 4;
    size_t au = ((size_t)(128 + (tid >> 1)) * 256 + n) * 8 + (size_t)(tid & 1) * 4;
    *(uint2*)(lhsF + hu) = make_uint2(hw0, hw1);
    *(uint2*)(lhsF + au) = make_uint2(aw0, aw1);
}

// ---------------- k_step: bf16 MFMA GEMM + LSTM gates ----------------
// grid (32, 4): ni (32 j x 4 gates = 128 cols), mi (64 rows)
// 256 threads = 4 waves: wm = wave&1 (32-row half), wn = wave>>1 (64-col half)
// Double-buffered LDS, single barrier per kc; x (kc>=32) staged via regs+cvt.
__global__ __launch_bounds__(256) void k_step(
    const unsigned short* __restrict__ lhsF,
    const float* __restrict__ x_t,    // x + t*DD, row stride TT*DD
    const unsigned short* __restrict__ Wsw,
    const float* __restrict__ b,
    float* __restrict__ c,
    float* __restrict__ out_t) {      // out + t*HH, row stride TT*HH
    const int ni = blockIdx.x, mi = blockIdx.y;
    const int tid = threadIdx.x;
    const int lane = tid & 63, wave = tid >> 6;
    const int wm = wave & 1, wn = wave >> 1;
    const int l15 = lane & 15, quad = lane >> 4;
    const int waveBase = tid & ~63;

    __shared__ __align__(16) char smem[49152];
    unsigned short* ldsA0 = (unsigned short*)smem;            // 8 KB each
    unsigned short* ldsA1 = (unsigned short*)(smem + 8192);
    unsigned short* ldsB0 = (unsigned short*)(smem + 16384);  // 16 KB each
    unsigned short* ldsB1 = (unsigned short*)(smem + 32768);

    floatx4 acc[2][4];
#pragma unroll
    for (int mt = 0; mt < 2; ++mt)
#pragma unroll
        for (int nt = 0; nt < 4; ++nt) acc[mt][nt] = (floatx4)0.f;

    const unsigned short* wTile = Wsw + (size_t)ni * (48 * 1024 * 8);

    // prologue: stage kc=0 (DMA path) into buffer 0
    {
        const unsigned short* bs = wTile;
#pragma unroll
        for (int i = 0; i < 4; ++i)
            async_copy16(bs + (size_t)(i * 256 + tid) * 8,
                         ldsB0 + (size_t)(i * 256 + waveBase) * 8);
        const unsigned short* as_ = lhsF + ((size_t)0 * 256 + mi * 64) * 8;
#pragma unroll
        for (int i = 0; i < 2; ++i) {
            int u = i * 256 + tid;
            int kq = u >> 6, mm = u & 63;
            async_copy16(as_ + ((size_t)kq * 256 + mm) * 8,
                         ldsA0 + (size_t)(i * 256 + waveBase) * 8);
        }
    }

#pragma unroll 2
    for (int kc = 0; kc < 48; ++kc) {
        unsigned short* curA = (kc & 1) ? ldsA1 : ldsA0;
        unsigned short* curB = (kc & 1) ? ldsB1 : ldsB0;
        unsigned short* nxtA = (kc & 1) ? ldsA0 : ldsA1;
        unsigned short* nxtB = (kc & 1) ? ldsB0 : ldsB1;
        const int kn = kc + 1;
        float4 xv00, xv01, xv10, xv11;
        bool xstage = false;

        __syncthreads();  // drains prev DMA (overlapped with prev compute) + read safety

        if (kn < 48) {
            const unsigned short* bs = wTile + (size_t)kn * 1024 * 8;
#pragma unroll
            for (int i = 0; i < 4; ++i)
                async_copy16(bs + (size_t)(i * 256 + tid) * 8,
                             nxtB + (size_t)(i * 256 + waveBase) * 8);
            if (kn < 32) {
                const unsigned short* as_ = lhsF + (((size_t)kn * 8) * 256 + mi * 64) * 8;
#pragma unroll
                for (int i = 0; i < 2; ++i) {
                    int u = i * 256 + tid;
                    int kq = u >> 6, mm = u & 63;
                    async_copy16(as_ + ((size_t)kq * 256 + mm) * 8,
                                 nxtA + (size_t)(i * 256 + waveBase) * 8);
                }
            } else {
                xstage = true;
                const int kx = (kn - 32) * 64;
                {
                    int u = tid;
                    int kq = u >> 6, mm = u & 63;
                    const float* sx = x_t + (size_t)(mi * 64 + mm) * (TT * DD) + kx + kq * 8;
                    xv00 = ((const float4*)sx)[0];
                    xv01 = ((const float4*)sx)[1];
                }
                {
                    int u = 256 + tid;
                    int kq = u >> 6, mm = u & 63;
                    const float* sx = x_t + (size_t)(mi * 64 + mm) * (TT * DD) + kx + kq * 8;
                    xv10 = ((const float4*)sx)[0];
                    xv11 = ((const float4*)sx)[1];
                }
            }
        }

        // compute on cur
#pragma unroll
        for (int ks = 0; ks < 2; ++ks) {
            const int kqq = ks * 4 + quad;
            short8 af[2], bfr[4];
#pragma unroll
            for (int mt = 0; mt < 2; ++mt)
                af[mt] = *(const short8*)(curA + (size_t)(kqq * 64 + wm * 32 + mt * 16 + l15) * 8);
#pragma unroll
            for (int nt = 0; nt < 4; ++nt)
                bfr[nt] = *(const short8*)(curB + (size_t)(kqq * 128 + wn * 64 + nt * 16 + l15) * 8);
#pragma unroll
            for (int mt = 0; mt < 2; ++mt)
#pragma unroll
                for (int nt = 0; nt < 4; ++nt)
                    acc[mt][nt] = __builtin_amdgcn_mfma_f32_16x16x32_bf16(
                        af[mt], bfr[nt], acc[mt][nt], 0, 0, 0);
        }

        if (xstage) {
            unsigned int w0 = f2bf(xv00.x) | (f2bf(xv00.y) << 16);
            unsigned int w1 = f2bf(xv00.z) | (f2bf(xv00.w) << 16);
            unsigned int w2 = f2bf(xv01.x) | (f2bf(xv01.y) << 16);
            unsigned int w3 = f2bf(xv01.z) | (f2bf(xv01.w) << 16);
            *(uint4*)(nxtA + (size_t)tid * 8) = make_uint4(w0, w1, w2, w3);
            w0 = f2bf(xv10.x) | (f2bf(xv10.y) << 16);
            w1 = f2bf(xv10.z) | (f2bf(xv10.w) << 16);
            w2 = f2bf(xv11.x) | (f2bf(xv11.y) << 16);
            w3 = f2bf(xv11.z) | (f2bf(xv11.w) << 16);
            *(uint4*)(nxtA + (size_t)(256 + tid) * 8) = make_uint4(w0, w1, w2, w3);
        }
    }

    // epilogue: exchange gates through LDS (reuse staging memory), then c/h update
    __syncthreads();
    float* asF = (float*)smem;  // 64 rows x 128 cc
#pragma unroll
    for (int mt = 0; mt < 2; ++mt)
#pragma unroll
        for (int nt = 0; nt < 4; ++nt)
#pragma unroll
            for (int r = 0; r < 4; ++r) {
                int row = wm * 32 + mt * 16 + quad * 4 + r;
                int cc = wn * 64 + nt * 16 + l15;
                asF[row * 128 + cc] = acc[mt][nt][r];
            }
    __syncthreads();

    const int j = tid & 31;
    const int jj = ni * 32 + j;
    const float bi = b[jj], bf_ = b[1024 + jj], bo = b[2048 + jj], bg = b[3072 + jj];
#pragma unroll
    for (int i = 0; i < 8; ++i) {
        int row = i * 8 + (tid >> 5);
        float ai  = asF[row * 128 + j]      + bi;
        float af2 = asF[row * 128 + 32 + j] + bf_;
        float ao  = asF[row * 128 + 64 + j] + bo;
        float ag  = asF[row * 128 + 96 + j] + bg;
        float iv = 1.f / (1.f + __expf(-ai));
        float fv = 1.f / (1.f + __expf(-af2));
        float ov = 1.f / (1.f + __expf(-ao));
        float gv = 1.f - 2.f / (__expf(2.f * ag) + 1.f);
        int n = mi * 64 + row;
        size_t ci = (size_t)n * HH + jj;
        float cold = c[ci];
        float cn = fv * cold + iv * gv;
        c[ci] = cn;
        float th = 1.f - 2.f / (__expf(2.f * cn) + 1.f);
        out_t[(size_t)n * (TT * HH) + jj] = ov * th;
    }
}

extern "C" void kernel_launch(void* const* d_in, const int* in_sizes, int n_in,
                              void* d_out, int out_size, void* d_ws, size_t ws_size,
                              hipStream_t stream) {
    const float* x     = (const float*)d_in[0];
    const float* A     = (const float*)d_in[1];
    const float* Wx    = (const float*)d_in[2];
    const float* Wh    = (const float*)d_in[3];
    const float* Wattn = (const float*)d_in[4];
    const float* b     = (const float*)d_in[5];
    float* out = (float*)d_out;

    char* w = (char*)d_ws;
    unsigned short* Wsw  = (unsigned short*)(w);                 // 25,165,824 B
    unsigned short* lhsF = (unsigned short*)(w + 25165824);      //  1,048,576 B
    unsigned short* Abf  = (unsigned short*)(w + 26214400);      //  8,388,608 B
    float* h0            = (float*)(w + 34603008);               //  1,048,576 B
    float* c             = (float*)(w + 35651584);               //  1,048,576 B

    k_convW<<<6144, 256, 0, stream>>>(Wh, Wattn, Wx, Wsw);
    k_convA_init<<<1024, 256, 0, stream>>>(A, Abf, h0, c);

    for (int t = 0; t < TT; ++t) {
        const float* hprev = (t == 0) ? h0 : out + (size_t)(t - 1) * HH;
        int hstride = (t == 0) ? HH : TT * HH;
        k_attn<<<NB, 256, 0, stream>>>(Abf, hprev, hstride, lhsF);
        k_step<<<dim3(32, 4), 256, 0, stream>>>(
            lhsF, x + (size_t)t * DD, Wsw, b, c, out + (size_t)t * HH);
    }
}

// Round 4
// 1350.547 us; speedup vs baseline: 11.4434x; 2.4427x over previous
//
#include <hip/hip_runtime.h>
#include <math.h>

#define NB 256
#define TT 64
#define DD 1024
#define HH 1024

typedef __attribute__((ext_vector_type(8))) short short8;
typedef __attribute__((ext_vector_type(4))) float floatx4;

__device__ inline unsigned short f2bf(float f) {
    unsigned int u = __builtin_bit_cast(unsigned int, f);
    u += 0x7fffu + ((u >> 16) & 1u);
    return (unsigned short)(u >> 16);
}
__device__ inline float bf2f(unsigned int h16) {
    unsigned int u = h16 << 16;
    return __builtin_bit_cast(float, u);
}

__device__ inline void async_copy16(const unsigned short* g, unsigned short* l) {
    __builtin_amdgcn_global_load_lds(
        (const __attribute__((address_space(1))) unsigned int*)(g),
        (__attribute__((address_space(3))) unsigned int*)(l), 16, 0, 0);
}

// ---------------- conv W: fp32 [k][4096] -> bf16 B-fragment tiles, N_b=64 ----------
// Tile (nj 0..63, kc 0..47): 512 units of 16B; unit = kq*64 + cc (kq 0..7, cc 0..63);
// holds W[k = kc*64+kq*8 + j][col = (cc>>4)*1024 + nj*16 + (cc&15)], j=0..7.
__global__ void k_convW(const float* __restrict__ Wh,
                        const float* __restrict__ Wattn,
                        const float* __restrict__ Wx,
                        unsigned short* __restrict__ Wsw) {
    int u = blockIdx.x * 256 + threadIdx.x;  // 0 .. 64*48*512-1
    int tile = u >> 9;
    int nj = tile / 48, kc = tile % 48;
    int within = u & 511;
    int kq = within >> 6, cc = within & 63;
    int k = kc * 64 + kq * 8;
    int col = (cc >> 4) * 1024 + nj * 16 + (cc & 15);
    const float* src;
    if (k < 1024)       src = Wh    + (size_t)k * 4096 + col;
    else if (k < 2048)  src = Wattn + (size_t)(k - 1024) * 4096 + col;
    else                src = Wx    + (size_t)(k - 2048) * 4096 + col;
    unsigned int w[4];
#pragma unroll
    for (int j = 0; j < 4; ++j) {
        unsigned int lo = f2bf(src[(size_t)(2 * j) * 4096]);
        unsigned int hi = f2bf(src[(size_t)(2 * j + 1) * 4096]);
        w[j] = lo | (hi << 16);
    }
    ((uint4*)Wsw)[u] = make_uint4(w[0], w[1], w[2], w[3]);
}

// ---------------- conv x: fp32 [m][t][d] -> bf16 A-fragment layout ----------------
// xF unit index = t*32768 + kq*256 + m ; holds x[m][t][kq*8 + j], j=0..7
__global__ void k_convX(const float* __restrict__ x, unsigned short* __restrict__ xF) {
    int u = blockIdx.x * 256 + threadIdx.x;  // 0 .. 64*128*256-1
    int t = u >> 15;
    int kq = (u >> 8) & 127;
    int m = u & 255;
    const float* src = x + (size_t)m * (TT * DD) + t * DD + kq * 8;
    float4 v0 = ((const float4*)src)[0];
    float4 v1 = ((const float4*)src)[1];
    unsigned int w0 = f2bf(v0.x) | (f2bf(v0.y) << 16);
    unsigned int w1 = f2bf(v0.z) | (f2bf(v0.w) << 16);
    unsigned int w2 = f2bf(v1.x) | (f2bf(v1.y) << 16);
    unsigned int w3 = f2bf(v1.z) | (f2bf(v1.w) << 16);
    ((uint4*)xF)[u] = make_uint4(w0, w1, w2, w3);
}

// ---------------- conv A -> bf16, plus h0 = c0 = mean ----------------
__global__ void k_convA_init(const float* __restrict__ A,
                             unsigned short* __restrict__ Abf,
                             float* __restrict__ h0,
                             float* __restrict__ c) {
    int idx = blockIdx.x * 256 + threadIdx.x;  // n*1024 + h
    const float4* ap = (const float4*)(A + (size_t)idx * 16);
    float4 v0 = ap[0], v1 = ap[1], v2 = ap[2], v3 = ap[3];
    float vs[16] = {v0.x, v0.y, v0.z, v0.w, v1.x, v1.y, v1.z, v1.w,
                    v2.x, v2.y, v2.z, v2.w, v3.x, v3.y, v3.z, v3.w};
    float s = 0.f;
    unsigned int w[8];
#pragma unroll
    for (int j = 0; j < 8; ++j) {
        s += vs[2 * j] + vs[2 * j + 1];
        w[j] = f2bf(vs[2 * j]) | (f2bf(vs[2 * j + 1]) << 16);
    }
    ((uint4*)Abf)[idx * 2]     = make_uint4(w[0], w[1], w[2], w[3]);
    ((uint4*)Abf)[idx * 2 + 1] = make_uint4(w[4], w[5], w[6], w[7]);
    s *= (1.f / 16.f);
    h0[idx] = s;
    c[idx] = s;
}

// ---------------- k_attn: attention + write h/attn into lhs fragment buffer ----------
// lhsF unit = kq*256 + n (kq 0..127 = h features, 128..255 = attn features)
__global__ __launch_bounds__(256) void k_attn(
    const unsigned short* __restrict__ Abf,
    const float* __restrict__ hprev, int hstride,
    unsigned short* __restrict__ lhsF) {
    const int n = blockIdx.x;
    const int tid = threadIdx.x;
    const int lane = tid & 63, wave = tid >> 6;

    float4 hv = *(const float4*)(hprev + (size_t)n * hstride + tid * 4);
    const uint4* ar = (const uint4*)(Abf + ((size_t)n * 1024 + tid * 4) * 16);

    float a[4][16];
#pragma unroll
    for (int r = 0; r < 4; ++r) {
        uint4 p0 = ar[r * 2], p1 = ar[r * 2 + 1];
        unsigned int ws[8] = {p0.x, p0.y, p0.z, p0.w, p1.x, p1.y, p1.z, p1.w};
#pragma unroll
        for (int j = 0; j < 8; ++j) {
            a[r][2 * j]     = bf2f(ws[j] & 0xffffu);
            a[r][2 * j + 1] = bf2f(ws[j] >> 16);
        }
    }
    float hvv[4] = {hv.x, hv.y, hv.z, hv.w};
    float s[16];
#pragma unroll
    for (int l = 0; l < 16; ++l) {
        float t = 0.f;
#pragma unroll
        for (int r = 0; r < 4; ++r) t += hvv[r] * a[r][l];
        s[l] = t;
    }

#pragma unroll
    for (int off = 32; off > 0; off >>= 1) {
#pragma unroll
        for (int l = 0; l < 16; ++l) s[l] += __shfl_xor(s[l], off, 64);
    }
    __shared__ float wred[4 * 16];
    if (lane == 0) {
#pragma unroll
        for (int l = 0; l < 16; ++l) wred[wave * 16 + l] = s[l];
    }
    __syncthreads();

    const float scale = 0.03125f;  // 1/sqrt(1024)
    float sv[16];
#pragma unroll
    for (int l = 0; l < 16; ++l)
        sv[l] = (wred[l] + wred[16 + l] + wred[32 + l] + wred[48 + l]) * scale;
    float mx = sv[0];
#pragma unroll
    for (int l = 1; l < 16; ++l) mx = fmaxf(mx, sv[l]);
    float e[16], sum = 0.f;
#pragma unroll
    for (int l = 0; l < 16; ++l) { e[l] = __expf(sv[l] - mx); sum += e[l]; }
    float inv = 1.f / sum;
#pragma unroll
    for (int l = 0; l < 16; ++l) e[l] *= inv;

    unsigned short hb[4], ab[4];
#pragma unroll
    for (int r = 0; r < 4; ++r) {
        float acc = 0.f;
#pragma unroll
        for (int l = 0; l < 16; ++l) acc += a[r][l] * e[l];
        ab[r] = f2bf(acc);
        hb[r] = f2bf(hvv[r]);
    }
    unsigned int hw0 = (unsigned int)hb[0] | ((unsigned int)hb[1] << 16);
    unsigned int hw1 = (unsigned int)hb[2] | ((unsigned int)hb[3] << 16);
    unsigned int aw0 = (unsigned int)ab[0] | ((unsigned int)ab[1] << 16);
    unsigned int aw1 = (unsigned int)ab[2] | ((unsigned int)ab[3] << 16);
    size_t hu = ((size_t)(tid >> 1) * 256 + n) * 8 + (size_t)(tid & 1) * 4;
    size_t au = ((size_t)(128 + (tid >> 1)) * 256 + n) * 8 + (size_t)(tid & 1) * 4;
    *(uint2*)(lhsF + hu) = make_uint2(hw0, hw1);
    *(uint2*)(lhsF + au) = make_uint2(aw0, aw1);
}

// ---------------- k_step: bf16 MFMA GEMM + LSTM gates, 4-stage async pipeline -------
// grid (64, 4): nj (16 j x 4 gates = 64 cols), mi (64 rows). 256 thr = 4 waves,
// wave tile 32x32 (wm = wave&1 row-half, wn = wave>>1 col-half).
// K = 3072 = 48 chunks of 64; kc<32 from lhsF (h|attn), kc>=32 from xF (x_t).
// Pipeline: 4 LDS buffers; raw s_waitcnt vmcnt(N)+s_barrier keeps 2-3 chunks of
// global_load_lds in flight across barriers (never drains to 0 -> latency hidden).
__global__ __launch_bounds__(256) void k_step(
    const unsigned short* __restrict__ lhsF,
    const unsigned short* __restrict__ xFt,   // xF + t*262144
    const unsigned short* __restrict__ Wsw,
    const float* __restrict__ b,
    float* __restrict__ c,
    float* __restrict__ out_t) {              // out + t*HH, row stride TT*HH
    const int nj = blockIdx.x, mi = blockIdx.y;
    const int tid = threadIdx.x;
    const int lane = tid & 63, wave = tid >> 6;
    const int wm = wave & 1, wn = wave >> 1;
    const int l15 = lane & 15, quad = lane >> 4;
    const int waveBase = tid & ~63;

    // 4 buffers x (A 4096 shorts | B 4096 shorts) = 64 KB
    __shared__ __align__(16) unsigned short lds[4 * 8192];

    floatx4 acc[2][2];
#pragma unroll
    for (int mt = 0; mt < 2; ++mt)
#pragma unroll
        for (int nt = 0; nt < 2; ++nt) acc[mt][nt] = (floatx4)0.f;

    const unsigned short* wTile = Wsw + (size_t)nj * (48 * 512 * 8);

    auto stage = [&](int kc, int buf) {
        unsigned short* la = lds + (size_t)buf * 8192;
        unsigned short* lb = la + 4096;
        const unsigned short* as_ = (kc < 32)
            ? lhsF + ((size_t)(kc * 8) * 256 + (size_t)mi * 64) * 8
            : xFt + ((size_t)((kc - 32) * 8) * 256 + (size_t)mi * 64) * 8;
#pragma unroll
        for (int i = 0; i < 2; ++i) {
            int idx = i * 256 + tid;
            int kq = idx >> 6, mm = idx & 63;
            async_copy16(as_ + ((size_t)kq * 256 + mm) * 8,
                         la + (size_t)(i * 256 + waveBase) * 8);
        }
        const unsigned short* bs = wTile + (size_t)kc * 512 * 8;
#pragma unroll
        for (int i = 0; i < 2; ++i) {
            int idx = i * 256 + tid;
            async_copy16(bs + (size_t)idx * 8,
                         lb + (size_t)(i * 256 + waveBase) * 8);
        }
    };

    auto compute = [&](int buf) {
        const unsigned short* la = lds + (size_t)buf * 8192;
        const unsigned short* lb = la + 4096;
#pragma unroll
        for (int ks = 0; ks < 2; ++ks) {
            const int kqq = ks * 4 + quad;
            short8 af[2], bfr[2];
#pragma unroll
            for (int mt = 0; mt < 2; ++mt)
                af[mt] = *(const short8*)(la + (size_t)(kqq * 64 + wm * 32 + mt * 16 + l15) * 8);
#pragma unroll
            for (int nt = 0; nt < 2; ++nt)
                bfr[nt] = *(const short8*)(lb + (size_t)(kqq * 64 + wn * 32 + nt * 16 + l15) * 8);
#pragma unroll
            for (int mt = 0; mt < 2; ++mt)
#pragma unroll
                for (int nt = 0; nt < 2; ++nt)
                    acc[mt][nt] = __builtin_amdgcn_mfma_f32_16x16x32_bf16(
                        af[mt], bfr[nt], acc[mt][nt], 0, 0, 0);
        }
    };

    stage(0, 0);
    stage(1, 1);
    stage(2, 2);  // 12 loads/wave outstanding

#pragma unroll 4
    for (int kc = 0; kc < 45; ++kc) {
        // wait until chunk kc's 4 loads retired (kc+1, kc+2 stay in flight)
        asm volatile("s_waitcnt vmcnt(8)\n\ts_barrier" ::: "memory");
        stage(kc + 3, (kc + 3) & 3);
        compute(kc & 3);
    }
    asm volatile("s_waitcnt vmcnt(8)\n\ts_barrier" ::: "memory");
    compute(45 & 3);
    asm volatile("s_waitcnt vmcnt(4)\n\ts_barrier" ::: "memory");
    compute(46 & 3);
    asm volatile("s_waitcnt vmcnt(0)\n\ts_barrier" ::: "memory");
    compute(47 & 3);

    // epilogue: exchange 64x64 fp32 partial tile through LDS, then gates + c/h
    __syncthreads();
    float* asF = (float*)lds;
#pragma unroll
    for (int mt = 0; mt < 2; ++mt)
#pragma unroll
        for (int nt = 0; nt < 2; ++nt)
#pragma unroll
            for (int r = 0; r < 4; ++r) {
                int row = wm * 32 + mt * 16 + quad * 4 + r;
                int cc = wn * 32 + nt * 16 + l15;
                asF[row * 64 + cc] = acc[mt][nt][r];
            }
    __syncthreads();

    const int j15 = tid & 15;
    const int jj = nj * 16 + j15;
    const float bi = b[jj], bf_ = b[1024 + jj], bo = b[2048 + jj], bg = b[3072 + jj];
#pragma unroll
    for (int i = 0; i < 4; ++i) {
        int cell = i * 256 + tid;
        int row = cell >> 4;
        float ai  = asF[row * 64 + j15]      + bi;
        float af2 = asF[row * 64 + 16 + j15] + bf_;
        float ao  = asF[row * 64 + 32 + j15] + bo;
        float ag  = asF[row * 64 + 48 + j15] + bg;
        float iv = 1.f / (1.f + __expf(-ai));
        float fv = 1.f / (1.f + __expf(-af2));
        float ov = 1.f / (1.f + __expf(-ao));
        float gv = 1.f - 2.f / (__expf(2.f * ag) + 1.f);
        int n = mi * 64 + row;
        size_t ci = (size_t)n * HH + jj;
        float cold = c[ci];
        float cn = fv * cold + iv * gv;
        c[ci] = cn;
        float th = 1.f - 2.f / (__expf(2.f * cn) + 1.f);
        out_t[(size_t)n * (TT * HH) + jj] = ov * th;
    }
}

extern "C" void kernel_launch(void* const* d_in, const int* in_sizes, int n_in,
                              void* d_out, int out_size, void* d_ws, size_t ws_size,
                              hipStream_t stream) {
    const float* x     = (const float*)d_in[0];
    const float* A     = (const float*)d_in[1];
    const float* Wx    = (const float*)d_in[2];
    const float* Wh    = (const float*)d_in[3];
    const float* Wattn = (const float*)d_in[4];
    const float* b     = (const float*)d_in[5];
    float* out = (float*)d_out;

    char* w = (char*)d_ws;
    unsigned short* Wsw  = (unsigned short*)(w);                 // 25,165,824 B
    unsigned short* xF   = (unsigned short*)(w + 25165824);      // 33,554,432 B
    unsigned short* lhsF = (unsigned short*)(w + 58720256);      //  1,048,576 B
    unsigned short* Abf  = (unsigned short*)(w + 59768832);      //  8,388,608 B
    float* h0            = (float*)(w + 68157440);               //  1,048,576 B
    float* c             = (float*)(w + 69206016);               //  1,048,576 B

    k_convW<<<6144, 256, 0, stream>>>(Wh, Wattn, Wx, Wsw);
    k_convX<<<8192, 256, 0, stream>>>(x, xF);
    k_convA_init<<<1024, 256, 0, stream>>>(A, Abf, h0, c);

    for (int t = 0; t < TT; ++t) {
        const float* hprev = (t == 0) ? h0 : out + (size_t)(t - 1) * HH;
        int hstride = (t == 0) ? HH : TT * HH;
        k_attn<<<NB, 256, 0, stream>>>(Abf, hprev, hstride, lhsF);
        k_step<<<dim3(64, 4), 256, 0, stream>>>(
            lhsF, xF + (size_t)t * 262144, Wsw, b, c, out + (size_t)t * HH);
    }
}